// Round 7
// baseline (163.491 us; speedup 1.0000x reference)
//
#include <hip/hip_runtime.h>
#include <math.h>

typedef __attribute__((ext_vector_type(8))) short bf16x8;
typedef __attribute__((ext_vector_type(4))) float f32x4;
typedef __attribute__((ext_vector_type(4))) int i32x4;
typedef __attribute__((ext_vector_type(4))) unsigned short u16x4;

#define LOG2E 1.4426950408889634f
#define LN2   0.6931471805599453f
#define FTINY 1.1754943508222875e-38f
#define MOFF  16.0f   // fixed base-2 LSE offset; logits provably < 12

// Problem constants (fixed by the reference)
constexpr int Dd = 64;
constexpr int Bb = 4096;
constexpr int Ss = 40960;
constexpr int BN = 256;               // batch cols per block in main kernel
constexpr int SCHUNK = 128;           // s-rows per LDS chunk (16 KiB)
constexpr int STILES = 64;            // grid.x of main kernel (4 blocks/CU)
constexpr int SPB = Ss / STILES;      // 640 s-rows per block
constexpr int NCHUNK = SPB / SCHUNK;  // 5
constexpr int NBLOCKS = STILES * (Bb / BN);   // 1024
constexpr int IDS_PER_BLOCK = Ss / NBLOCKS;   // 40

// K1 grid segments
constexpr int SAMP_BLOCKS = Ss / 16;             // 2560
constexpr int USER_BLOCKS = (Bb * Dd / 4) / 256; // 256
constexpr int C2_BLOCKS   = Ss / 256;            // 160

static __device__ __forceinline__ unsigned short f2bf(float x) {
    unsigned int u = __float_as_uint(x);
    u += 0x7fffu + ((u >> 16) & 1u);   // RNE
    return (unsigned short)(u >> 16);
}

// KEEP powf(1.0f-p, T): must reproduce the reference's fp32 quantization of (1-p).
static __device__ __forceinline__ float neg_log_expected(int id, float invLogV1, float T) {
    float f = (float)id;
    float p = log1pf(1.0f / (f + 1.0f)) * invLogV1;
    float pw = powf(1.0f - p, T);
    float se = fmaxf(1.0f - pw, FTINY);
    return -logf(se);
}

// ---- K1: samp gather->bf16 | bitmap zero + cnt | user->bf16*LOG2E | c2' ----
__global__ void k_prep(const float* __restrict__ user, const float* __restrict__ item,
                       const float* __restrict__ bias, const int* __restrict__ sampled,
                       const int* __restrict__ ntries,
                       unsigned short* __restrict__ Ebf, unsigned short* __restrict__ Ubf,
                       float* __restrict__ c2, unsigned int* __restrict__ bm,
                       unsigned int* __restrict__ cnt, float invLogV1, int nbmw, int zb) {
    const int bid = blockIdx.x, tid = threadIdx.x;
    if (bid < SAMP_BLOCKS) {
        const int ri = tid >> 4, c = tid & 15;
        const int s = bid * 16 + ri;
        const int sid = sampled[s];
        f32x4 v = *(const f32x4*)(item + (size_t)sid * Dd + c * 4);
        u16x4 o;
        o[0] = f2bf(v[0]); o[1] = f2bf(v[1]); o[2] = f2bf(v[2]); o[3] = f2bf(v[3]);
        *(u16x4*)(Ebf + (size_t)s * Dd + c * 4) = o;
    } else if (bid < SAMP_BLOCKS + zb) {
        const int z = bid - SAMP_BLOCKS;
        if (z == 0 && tid == 0) *cnt = 0u;
        const int base = (z * 256 + tid) * 4;
        if (base + 3 < nbmw) {
            i32x4 zz = {0, 0, 0, 0};
            *(i32x4*)((int*)bm + base) = zz;
        } else {
            for (int i = base; i < nbmw; ++i) bm[i] = 0u;
        }
    } else if (bid < SAMP_BLOCKS + zb + USER_BLOCKS) {
        const int i = (bid - SAMP_BLOCKS - zb) * 256 + tid;
        f32x4 v = *(const f32x4*)(user + (size_t)i * 4);
        u16x4 o;
        o[0] = f2bf(v[0] * LOG2E); o[1] = f2bf(v[1] * LOG2E);
        o[2] = f2bf(v[2] * LOG2E); o[3] = f2bf(v[3] * LOG2E);
        *(u16x4*)(Ubf + (size_t)i * 4) = o;
    } else {
        const int s = (bid - SAMP_BLOCKS - zb - USER_BLOCKS) * 256 + tid;
        const int sid = sampled[s];
        const float T = (float)ntries[0];
        c2[s] = (bias[sid] + neg_log_expected(sid, invLogV1, T)) * LOG2E - MOFF;
    }
}

// ---- K2: bitmap scatter + fused GEMM (base-2, c2' in acc) + sum-of-exp2 partials ----
// Bitmap SET here (zeroed in k_prep, read in k_final): kernel boundaries give ordering.
__global__ __launch_bounds__(256, 4) void ssl_main(
    const unsigned short* __restrict__ Ebf, const unsigned short* __restrict__ Ubf,
    const float* __restrict__ c2, const int* __restrict__ sampled,
    unsigned int* __restrict__ bm, float* __restrict__ partials)
{
    __shared__ __align__(16) unsigned short lds[SCHUNK * Dd];   // 16 KiB
    const int tid = threadIdx.x;
    const int w = tid >> 6, l = tid & 63;
    const int g16 = l >> 4, l16 = l & 15;
    const int stile = blockIdx.x, btile = blockIdx.y;

    // scatter membership bits (idempotent)
    const int fid = stile + STILES * btile;
    if (tid < IDS_PER_BLOCK) {
        const int sid = sampled[fid * IDS_PER_BLOCK + tid];
        atomicOr(&bm[sid >> 5], 1u << (sid & 31));
    }

    const int s0 = stile * SPB;
    const int colb = btile * BN + w * 64;   // 64 batch cols per wave
    // 8 B-fragments (U rows, pre-scaled by LOG2E): 4 col-groups x 2 K-halves
    bf16x8 bf[4][2];
    #pragma unroll
    for (int g = 0; g < 4; ++g) {
        const unsigned short* up = Ubf + (size_t)(colb + g * 16 + l16) * Dd + g16 * 8;
        bf[g][0] = *(const bf16x8*)(up);
        bf[g][1] = *(const bf16x8*)(up + 32);
    }

    float rl0 = 0.f, rl1 = 0.f, rl2 = 0.f, rl3 = 0.f;

    // staging: 4 x 16B per thread, linear LDS dest, source pre-swizzled (chunk ^= row&7)
    const int srow = tid >> 3, scs = tid & 7;
    const int csrc = scs ^ (srow & 7);
    const unsigned short* stgp = Ebf + (size_t)(s0 + srow) * Dd + csrc * 8;
    bf16x8 stg0 = *(const bf16x8*)(stgp);
    bf16x8 stg1 = *(const bf16x8*)(stgp + 32 * Dd);   // +32/64/96 rows: same swizzle (mod 8)
    bf16x8 stg2 = *(const bf16x8*)(stgp + 64 * Dd);
    bf16x8 stg3 = *(const bf16x8*)(stgp + 96 * Dd);
    const float* c2b = c2 + s0 + g16 * 4;

    for (int ch = 0; ch < NCHUNK; ++ch) {
        __syncthreads();                             // previous chunk consumed
        *(bf16x8*)(lds + tid * 8)           = stg0;  // rows  0..31
        *(bf16x8*)(lds + tid * 8 + 32 * Dd) = stg1;  // rows 32..63
        *(bf16x8*)(lds + tid * 8 + 64 * Dd) = stg2;  // rows 64..95
        *(bf16x8*)(lds + tid * 8 + 96 * Dd) = stg3;  // rows 96..127
        if (ch + 1 < NCHUNK) {
            const unsigned short* np = stgp + (size_t)(ch + 1) * SCHUNK * Dd;
            stg0 = *(const bf16x8*)(np);
            stg1 = *(const bf16x8*)(np + 32 * Dd);
            stg2 = *(const bf16x8*)(np + 64 * Dd);
            stg3 = *(const bf16x8*)(np + 96 * Dd);
        }
        __syncthreads();

        const float* c2c = c2b + ch * SCHUNK;
        #pragma unroll
        for (int t = 0; t < 8; ++t) {
            const int r = t * 16 + l16;
            const int sw = r & 7;
            const bf16x8 a0 = *(const bf16x8*)(lds + r * Dd + (((g16    ) ^ sw) << 3));
            const bf16x8 a1 = *(const bf16x8*)(lds + r * Dd + (((g16 + 4) ^ sw) << 3));
            const f32x4 cc = *(const f32x4*)(c2c + t * 16);
            #pragma unroll
            for (int g = 0; g < 4; ++g) {
                f32x4 acc = __builtin_amdgcn_mfma_f32_16x16x32_bf16(a0, bf[g][0], cc, 0, 0, 0);
                acc = __builtin_amdgcn_mfma_f32_16x16x32_bf16(a1, bf[g][1], acc, 0, 0, 0);
                // no max tracking: logits - MOFF in [-20, -4]; exact fp32 sums
                float e = (__builtin_amdgcn_exp2f(acc[0]) + __builtin_amdgcn_exp2f(acc[1]))
                        + (__builtin_amdgcn_exp2f(acc[2]) + __builtin_amdgcn_exp2f(acc[3]));
                if      (g == 0) rl0 += e;
                else if (g == 1) rl1 += e;
                else if (g == 2) rl2 += e;
                else             rl3 += e;
            }
        }
    }

    // sum across the 4 lane-groups (same col, different s-rows): pure adds
    rl0 += __shfl_xor(rl0, 16); rl0 += __shfl_xor(rl0, 32);
    rl1 += __shfl_xor(rl1, 16); rl1 += __shfl_xor(rl1, 32);
    rl2 += __shfl_xor(rl2, 16); rl2 += __shfl_xor(rl2, 32);
    rl3 += __shfl_xor(rl3, 16); rl3 += __shfl_xor(rl3, 32);
    if (l < 16) {
        partials[(size_t)(colb +  0 + l16) * STILES + stile] = rl0;
        partials[(size_t)(colb + 16 + l16) * STILES + stile] = rl1;
        partials[(size_t)(colb + 32 + l16) * STILES + stile] = rl2;
        partials[(size_t)(colb + 48 + l16) * STILES + stile] = rl3;
    }
}

// ---- K3: finalize (4 lanes per row) + last-block mean -> out ----
__global__ void k_final(const float* __restrict__ user, const float* __restrict__ item,
                        const float* __restrict__ bias, const int* __restrict__ posids,
                        const int* __restrict__ ntries, const float* __restrict__ partials,
                        const unsigned int* __restrict__ bm,
                        float* __restrict__ bsums, unsigned int* __restrict__ cnt,
                        float* __restrict__ out, float invLogV1) {
    const int tid = threadIdx.x, sub = tid & 3;
    const int b = blockIdx.x * 64 + (tid >> 2);
    const int pid = posids[b];
    const float T = (float)ntries[0];
    // exact fp32 dot(u_b, item[pid]), 16 elems per lane
    const f32x4* up = (const f32x4*)(user + (size_t)b * Dd + sub * 16);
    const f32x4* ep = (const f32x4*)(item + (size_t)pid * Dd + sub * 16);
    f32x4 dv = {0.f, 0.f, 0.f, 0.f};
    #pragma unroll
    for (int i = 0; i < 4; ++i) {
        f32x4 uu = up[i], ee = ep[i];
        dv[0] = fmaf(uu[0], ee[0], dv[0]); dv[1] = fmaf(uu[1], ee[1], dv[1]);
        dv[2] = fmaf(uu[2], ee[2], dv[2]); dv[3] = fmaf(uu[3], ee[3], dv[3]);
    }
    float d = (dv[0] + dv[1]) + (dv[2] + dv[3]);
    d += __shfl_xor(d, 1); d += __shfl_xor(d, 2);
    // sum of 64 partials, 16 per lane
    const float* pp = partials + (size_t)b * STILES + sub * 16;
    float S = 0.f;
    #pragma unroll
    for (int i = 0; i < 4; ++i) {
        f32x4 pv = *(const f32x4*)(pp + i * 4);
        S += ((pv[0] + pv[1]) + (pv[2] + pv[3]));
    }
    S += __shfl_xor(S, 1); S += __shfl_xor(S, 2);

    const float pb2 = (d + bias[pid] + neg_log_expected(pid, invLogV1, T)) * LOG2E;
    // accidental hit: hit row IS item[pid] -> its term cancels the pos column exactly
    const bool hit = (bm[pid >> 5] >> (pid & 31)) & 1u;
    if (!hit) S += __builtin_amdgcn_exp2f(pb2 - MOFF);
    float loss = (MOFF + log2f(S) - pb2) * LN2; // each b counted 4x (div by 4 at end)

    #pragma unroll
    for (int off = 1; off < 64; off <<= 1) loss += __shfl_xor(loss, off);
    __shared__ float wsum[4];
    if ((tid & 63) == 0) wsum[tid >> 6] = loss;
    __syncthreads();
    if (tid == 0) {
        bsums[blockIdx.x] = wsum[0] + wsum[1] + wsum[2] + wsum[3];
        __threadfence();
        if (atomicAdd(cnt, 1u) == 63u) {   // last block: deterministic ordered sum
            __threadfence();
            float tot = 0.f;
            for (int i = 0; i < 64; ++i) tot += bsums[i];
            out[0] = tot * (1.0f / (4.0f * (float)Bb));
        }
    }
}

extern "C" void kernel_launch(void* const* d_in, const int* in_sizes, int n_in,
                              void* d_out, int out_size, void* d_ws, size_t ws_size,
                              hipStream_t stream) {
    (void)n_in; (void)out_size; (void)ws_size;
    const float* user    = (const float*)d_in[0];
    const float* item    = (const float*)d_in[1];
    const float* bias    = (const float*)d_in[2];
    const int*   posids  = (const int*)d_in[3];
    const int*   sampled = (const int*)d_in[4];
    const int*   ntries  = (const int*)d_in[5];
    float* out = (float*)d_out;

    const int V = in_sizes[2];
    const float invLogV1 = 1.0f / logf((float)V + 1.0f);
    const int nbmw = (V + 31) / 32;
    const int zb = (nbmw + 1023) / 1024;

    char* p = (char*)d_ws;
    auto alloc = [&](size_t bytes) {
        char* r = p;
        p += (bytes + 255) & ~(size_t)255;
        return r;
    };
    unsigned short* Ebf     = (unsigned short*)alloc((size_t)Ss * Dd * 2);
    unsigned short* Ubf     = (unsigned short*)alloc((size_t)Bb * Dd * 2);
    float*          c2      = (float*)alloc((size_t)Ss * 4);
    float*          partial = (float*)alloc((size_t)Bb * STILES * 4);
    unsigned int*   bm      = (unsigned int*)alloc((size_t)nbmw * 4);
    float*          bsums   = (float*)alloc(64 * 4);
    unsigned int*   cnt     = (unsigned int*)alloc(256);

    k_prep<<<SAMP_BLOCKS + zb + USER_BLOCKS + C2_BLOCKS, 256, 0, stream>>>(
        user, item, bias, sampled, ntries, Ebf, Ubf, c2, bm, cnt, invLogV1, nbmw, zb);
    ssl_main<<<dim3(STILES, Bb / BN), 256, 0, stream>>>(Ebf, Ubf, c2, sampled, bm, partial);
    k_final<<<Bb / 64, 256, 0, stream>>>(user, item, bias, posids, ntries,
                                         partial, bm, bsums, cnt, out, invLogV1);
}

// Round 8
// 52.610 us; speedup vs baseline: 3.1076x; 3.1076x over previous
//
#include <hip/hip_runtime.h>
#include <math.h>

typedef __attribute__((ext_vector_type(8))) short bf16x8;
typedef __attribute__((ext_vector_type(4))) float f32x4;
typedef __attribute__((ext_vector_type(4))) int i32x4;
typedef __attribute__((ext_vector_type(4))) unsigned short u16x4;

#define LOG2E 1.4426950408889634f
#define LN2   0.6931471805599453f
#define FTINY 1.1754943508222875e-38f
#define MOFF  16.0f   // fixed base-2 LSE offset; logits provably < 12

// Problem constants (fixed by the reference)
constexpr int Dd = 64;
constexpr int Bb = 4096;
constexpr int Ss = 40960;
constexpr int BN = 256;               // batch cols per block in main kernel
constexpr int SCHUNK = 128;           // s-rows per LDS chunk (16 KiB)
constexpr int STILES = 64;            // grid.x of main kernel (4 blocks/CU target)
constexpr int SPB = Ss / STILES;      // 640 s-rows per block
constexpr int NCHUNK = SPB / SCHUNK;  // 5
constexpr int NBLOCKS = STILES * (Bb / BN);   // 1024
constexpr int IDS_PER_BLOCK = Ss / NBLOCKS;   // 40

// K1 grid segments
constexpr int SAMP_BLOCKS = Ss / 16;             // 2560
constexpr int USER_BLOCKS = (Bb * Dd / 4) / 256; // 256
constexpr int C2_BLOCKS   = Ss / 256;            // 160

static __device__ __forceinline__ unsigned short f2bf(float x) {
    unsigned int u = __float_as_uint(x);
    u += 0x7fffu + ((u >> 16) & 1u);   // RNE
    return (unsigned short)(u >> 16);
}

// KEEP powf(1.0f-p, T): must reproduce the reference's fp32 quantization of (1-p).
static __device__ __forceinline__ float neg_log_expected(int id, float invLogV1, float T) {
    float f = (float)id;
    float p = log1pf(1.0f / (f + 1.0f)) * invLogV1;
    float pw = powf(1.0f - p, T);
    float se = fmaxf(1.0f - pw, FTINY);
    return -logf(se);
}

// ---- K1: samp gather->bf16 | bitmap zero + cnt | user->bf16*LOG2E | c2' ----
__global__ void k_prep(const float* __restrict__ user, const float* __restrict__ item,
                       const float* __restrict__ bias, const int* __restrict__ sampled,
                       const int* __restrict__ ntries,
                       unsigned short* __restrict__ Ebf, unsigned short* __restrict__ Ubf,
                       float* __restrict__ c2, unsigned int* __restrict__ bm,
                       unsigned int* __restrict__ cnt, float invLogV1, int nbmw, int zb) {
    const int bid = blockIdx.x, tid = threadIdx.x;
    if (bid < SAMP_BLOCKS) {
        const int ri = tid >> 4, c = tid & 15;
        const int s = bid * 16 + ri;
        const int sid = sampled[s];
        f32x4 v = *(const f32x4*)(item + (size_t)sid * Dd + c * 4);
        u16x4 o;
        o[0] = f2bf(v[0]); o[1] = f2bf(v[1]); o[2] = f2bf(v[2]); o[3] = f2bf(v[3]);
        *(u16x4*)(Ebf + (size_t)s * Dd + c * 4) = o;
    } else if (bid < SAMP_BLOCKS + zb) {
        const int z = bid - SAMP_BLOCKS;
        if (z == 0 && tid == 0) *cnt = 0u;
        const int base = (z * 256 + tid) * 4;
        if (base + 3 < nbmw) {
            i32x4 zz = {0, 0, 0, 0};
            *(i32x4*)((int*)bm + base) = zz;
        } else {
            for (int i = base; i < nbmw; ++i) bm[i] = 0u;
        }
    } else if (bid < SAMP_BLOCKS + zb + USER_BLOCKS) {
        const int i = (bid - SAMP_BLOCKS - zb) * 256 + tid;
        f32x4 v = *(const f32x4*)(user + (size_t)i * 4);
        u16x4 o;
        o[0] = f2bf(v[0] * LOG2E); o[1] = f2bf(v[1] * LOG2E);
        o[2] = f2bf(v[2] * LOG2E); o[3] = f2bf(v[3] * LOG2E);
        *(u16x4*)(Ubf + (size_t)i * 4) = o;
    } else {
        const int s = (bid - SAMP_BLOCKS - zb - USER_BLOCKS) * 256 + tid;
        const int sid = sampled[s];
        const float T = (float)ntries[0];
        c2[s] = (bias[sid] + neg_log_expected(sid, invLogV1, T)) * LOG2E - MOFF;
    }
}

// ---- K2: bitmap scatter + fused GEMM (base-2, c2' in acc) + sum-of-exp2 partials ----
// Bitmap SET here (zeroed in k_prep, read in k_final): kernel boundaries give ordering.
// NOTE: no min-waves clamp — R7's __launch_bounds__(256,4) forced 64 VGPR -> 650 MB of
// scratch spill traffic (measured). Natural allocation (~96-128 VGPR) still gives 4 blk/CU.
__global__ __launch_bounds__(256) void ssl_main(
    const unsigned short* __restrict__ Ebf, const unsigned short* __restrict__ Ubf,
    const float* __restrict__ c2, const int* __restrict__ sampled,
    unsigned int* __restrict__ bm, float* __restrict__ partials)
{
    __shared__ __align__(16) unsigned short lds[SCHUNK * Dd];   // 16 KiB
    const int tid = threadIdx.x;
    const int w = tid >> 6, l = tid & 63;
    const int g16 = l >> 4, l16 = l & 15;
    const int stile = blockIdx.x, btile = blockIdx.y;

    // scatter membership bits (idempotent)
    const int fid = stile + STILES * btile;
    if (tid < IDS_PER_BLOCK) {
        const int sid = sampled[fid * IDS_PER_BLOCK + tid];
        atomicOr(&bm[sid >> 5], 1u << (sid & 31));
    }

    const int s0 = stile * SPB;
    const int colb = btile * BN + w * 64;   // 64 batch cols per wave
    // 8 B-fragments (U rows, pre-scaled by LOG2E): 4 col-groups x 2 K-halves
    bf16x8 bf[4][2];
    #pragma unroll
    for (int g = 0; g < 4; ++g) {
        const unsigned short* up = Ubf + (size_t)(colb + g * 16 + l16) * Dd + g16 * 8;
        bf[g][0] = *(const bf16x8*)(up);
        bf[g][1] = *(const bf16x8*)(up + 32);
    }

    float rl0 = 0.f, rl1 = 0.f, rl2 = 0.f, rl3 = 0.f;

    // staging: 4 x 16B per thread, linear LDS dest, source pre-swizzled (chunk ^= row&7)
    const int srow = tid >> 3, scs = tid & 7;
    const int csrc = scs ^ (srow & 7);
    const unsigned short* stgp = Ebf + (size_t)(s0 + srow) * Dd + csrc * 8;
    bf16x8 stg0 = *(const bf16x8*)(stgp);
    bf16x8 stg1 = *(const bf16x8*)(stgp + 32 * Dd);   // +32/64/96 rows: same swizzle (mod 8)
    bf16x8 stg2 = *(const bf16x8*)(stgp + 64 * Dd);
    bf16x8 stg3 = *(const bf16x8*)(stgp + 96 * Dd);
    const float* c2b = c2 + s0 + g16 * 4;

    for (int ch = 0; ch < NCHUNK; ++ch) {
        __syncthreads();                             // previous chunk consumed
        *(bf16x8*)(lds + tid * 8)           = stg0;  // rows  0..31
        *(bf16x8*)(lds + tid * 8 + 32 * Dd) = stg1;  // rows 32..63
        *(bf16x8*)(lds + tid * 8 + 64 * Dd) = stg2;  // rows 64..95
        *(bf16x8*)(lds + tid * 8 + 96 * Dd) = stg3;  // rows 96..127
        if (ch + 1 < NCHUNK) {
            const unsigned short* np = stgp + (size_t)(ch + 1) * SCHUNK * Dd;
            stg0 = *(const bf16x8*)(np);
            stg1 = *(const bf16x8*)(np + 32 * Dd);
            stg2 = *(const bf16x8*)(np + 64 * Dd);
            stg3 = *(const bf16x8*)(np + 96 * Dd);
        }
        __syncthreads();

        const float* c2c = c2b + ch * SCHUNK;
        #pragma unroll
        for (int t = 0; t < 8; ++t) {
            const int r = t * 16 + l16;
            const int sw = r & 7;
            const bf16x8 a0 = *(const bf16x8*)(lds + r * Dd + (((g16    ) ^ sw) << 3));
            const bf16x8 a1 = *(const bf16x8*)(lds + r * Dd + (((g16 + 4) ^ sw) << 3));
            const f32x4 cc = *(const f32x4*)(c2c + t * 16);
            #pragma unroll
            for (int g = 0; g < 4; ++g) {
                f32x4 acc = __builtin_amdgcn_mfma_f32_16x16x32_bf16(a0, bf[g][0], cc, 0, 0, 0);
                acc = __builtin_amdgcn_mfma_f32_16x16x32_bf16(a1, bf[g][1], acc, 0, 0, 0);
                // no max tracking: logits - MOFF in [-20, -4]; exact fp32 sums
                float e = (__builtin_amdgcn_exp2f(acc[0]) + __builtin_amdgcn_exp2f(acc[1]))
                        + (__builtin_amdgcn_exp2f(acc[2]) + __builtin_amdgcn_exp2f(acc[3]));
                if      (g == 0) rl0 += e;
                else if (g == 1) rl1 += e;
                else if (g == 2) rl2 += e;
                else             rl3 += e;
            }
        }
    }

    // sum across the 4 lane-groups (same col, different s-rows): pure adds
    rl0 += __shfl_xor(rl0, 16); rl0 += __shfl_xor(rl0, 32);
    rl1 += __shfl_xor(rl1, 16); rl1 += __shfl_xor(rl1, 32);
    rl2 += __shfl_xor(rl2, 16); rl2 += __shfl_xor(rl2, 32);
    rl3 += __shfl_xor(rl3, 16); rl3 += __shfl_xor(rl3, 32);
    if (l < 16) {
        partials[(size_t)(colb +  0 + l16) * STILES + stile] = rl0;
        partials[(size_t)(colb + 16 + l16) * STILES + stile] = rl1;
        partials[(size_t)(colb + 32 + l16) * STILES + stile] = rl2;
        partials[(size_t)(colb + 48 + l16) * STILES + stile] = rl3;
    }
}

// ---- K3: finalize (4 lanes per row) + last-block mean -> out ----
__global__ void k_final(const float* __restrict__ user, const float* __restrict__ item,
                        const float* __restrict__ bias, const int* __restrict__ posids,
                        const int* __restrict__ ntries, const float* __restrict__ partials,
                        const unsigned int* __restrict__ bm,
                        float* __restrict__ bsums, unsigned int* __restrict__ cnt,
                        float* __restrict__ out, float invLogV1) {
    const int tid = threadIdx.x, sub = tid & 3;
    const int b = blockIdx.x * 64 + (tid >> 2);
    const int pid = posids[b];
    const float T = (float)ntries[0];
    // exact fp32 dot(u_b, item[pid]), 16 elems per lane
    const f32x4* up = (const f32x4*)(user + (size_t)b * Dd + sub * 16);
    const f32x4* ep = (const f32x4*)(item + (size_t)pid * Dd + sub * 16);
    f32x4 dv = {0.f, 0.f, 0.f, 0.f};
    #pragma unroll
    for (int i = 0; i < 4; ++i) {
        f32x4 uu = up[i], ee = ep[i];
        dv[0] = fmaf(uu[0], ee[0], dv[0]); dv[1] = fmaf(uu[1], ee[1], dv[1]);
        dv[2] = fmaf(uu[2], ee[2], dv[2]); dv[3] = fmaf(uu[3], ee[3], dv[3]);
    }
    float d = (dv[0] + dv[1]) + (dv[2] + dv[3]);
    d += __shfl_xor(d, 1); d += __shfl_xor(d, 2);
    // sum of 64 partials, 16 per lane
    const float* pp = partials + (size_t)b * STILES + sub * 16;
    float S = 0.f;
    #pragma unroll
    for (int i = 0; i < 4; ++i) {
        f32x4 pv = *(const f32x4*)(pp + i * 4);
        S += ((pv[0] + pv[1]) + (pv[2] + pv[3]));
    }
    S += __shfl_xor(S, 1); S += __shfl_xor(S, 2);

    const float pb2 = (d + bias[pid] + neg_log_expected(pid, invLogV1, T)) * LOG2E;
    // accidental hit: hit row IS item[pid] -> its term cancels the pos column exactly
    const bool hit = (bm[pid >> 5] >> (pid & 31)) & 1u;
    if (!hit) S += __builtin_amdgcn_exp2f(pb2 - MOFF);
    float loss = (MOFF + log2f(S) - pb2) * LN2; // each b counted 4x (div by 4 at end)

    #pragma unroll
    for (int off = 1; off < 64; off <<= 1) loss += __shfl_xor(loss, off);
    __shared__ float wsum[4];
    if ((tid & 63) == 0) wsum[tid >> 6] = loss;
    __syncthreads();
    if (tid == 0) {
        bsums[blockIdx.x] = wsum[0] + wsum[1] + wsum[2] + wsum[3];
        __threadfence();
        if (atomicAdd(cnt, 1u) == 63u) {   // last block: deterministic ordered sum
            __threadfence();
            float tot = 0.f;
            for (int i = 0; i < 64; ++i) tot += bsums[i];
            out[0] = tot * (1.0f / (4.0f * (float)Bb));
        }
    }
}

extern "C" void kernel_launch(void* const* d_in, const int* in_sizes, int n_in,
                              void* d_out, int out_size, void* d_ws, size_t ws_size,
                              hipStream_t stream) {
    (void)n_in; (void)out_size; (void)ws_size;
    const float* user    = (const float*)d_in[0];
    const float* item    = (const float*)d_in[1];
    const float* bias    = (const float*)d_in[2];
    const int*   posids  = (const int*)d_in[3];
    const int*   sampled = (const int*)d_in[4];
    const int*   ntries  = (const int*)d_in[5];
    float* out = (float*)d_out;

    const int V = in_sizes[2];
    const float invLogV1 = 1.0f / logf((float)V + 1.0f);
    const int nbmw = (V + 31) / 32;
    const int zb = (nbmw + 1023) / 1024;

    char* p = (char*)d_ws;
    auto alloc = [&](size_t bytes) {
        char* r = p;
        p += (bytes + 255) & ~(size_t)255;
        return r;
    };
    unsigned short* Ebf     = (unsigned short*)alloc((size_t)Ss * Dd * 2);
    unsigned short* Ubf     = (unsigned short*)alloc((size_t)Bb * Dd * 2);
    float*          c2      = (float*)alloc((size_t)Ss * 4);
    float*          partial = (float*)alloc((size_t)Bb * STILES * 4);
    unsigned int*   bm      = (unsigned int*)alloc((size_t)nbmw * 4);
    float*          bsums   = (float*)alloc(64 * 4);
    unsigned int*   cnt     = (unsigned int*)alloc(256);

    k_prep<<<SAMP_BLOCKS + zb + USER_BLOCKS + C2_BLOCKS, 256, 0, stream>>>(
        user, item, bias, sampled, ntries, Ebf, Ubf, c2, bm, cnt, invLogV1, nbmw, zb);
    ssl_main<<<dim3(STILES, Bb / BN), 256, 0, stream>>>(Ebf, Ubf, c2, sampled, bm, partial);
    k_final<<<Bb / 64, 256, 0, stream>>>(user, item, bias, posids, ntries,
                                         partial, bm, bsums, cnt, out, invLogV1);
}